// Round 2
// baseline (168.035 us; speedup 1.0000x reference)
//
#include <hip/hip_runtime.h>

// SIRD RK4, round 15: single self-contained wave — no LDS, no barrier, no
// producer/consumer split.
//
// R14 post-mortem: v_pk_*_f32 issues at 2 scalar-slot equivalents for a lone
// wave (15 pk ops == 30 slots == R13's 29.4 measured slots; dispatch time
// identical). The currency is FP32-lane-ops at ~4 cyc each. Revert to the
// scalar 22-slot core.
//
// R13's handoff surcharge (ds_write issue + lgkmcnt + s_barrier machinery,
// ~6 slots/tstep) exceeds what the consumer offloads (2 D-FMAs/tstep + one
// 16B store per 2 tsteps, ~3 slots/tstep). So: one wave does everything.
// Static count per 2 tsteps: 44 core + 4 D-fma + 1 global_store_dwordx4
// (fire-and-forget) + ~2 packing movs ~= 51 slots -> ~25.5 slots/tstep vs
// 28.7 measured effective in R13/R14.
//
// State (sigma, I), sigma = c*S: d(sigma) = -c*(sigma*I), dI = fma(-gm,I,m).
// D from RK4-preserved invariant: D = fma(-kD/c, sigma, fma(-kD, I, kD*N)).
// Trajectory math bit-identical to R13/R14 (same RK4_STEP op order).

#define N_POP 1.0e7f
#define T_PTS 2048

// One RK4 step (h=1), 22 VALU slots, updates SG and IV in place.
#define RK4_STEP(SG, IV)                                                     \
    do {                                                                     \
        const float m1 = (SG) * (IV);                                        \
        const float g1 = __builtin_fmaf(ngm, (IV), m1);                      \
        const float s2 = __builtin_fmaf(nch2, m1, (SG));                     \
        const float i2 = __builtin_fmaf(h2, g1, (IV));                       \
        const float m2 = s2 * i2;                                            \
        const float g2 = __builtin_fmaf(ngm, i2, m2);                        \
        const float s3 = __builtin_fmaf(nch2, m2, (SG));                     \
        const float i3 = __builtin_fmaf(h2, g2, (IV));                       \
        const float m3 = s3 * i3;                                            \
        const float g3 = __builtin_fmaf(ngm, i3, m3);                        \
        const float s4 = __builtin_fmaf(nch, m3, (SG));                      \
        const float i4 = (IV) + g3;                                          \
        const float m4 = s4 * i4;                                            \
        const float g4 = __builtin_fmaf(ngm, i4, m4);                        \
        float tm = __builtin_fmaf(2.0f, m2, m1);                             \
        tm = __builtin_fmaf(2.0f, m3, tm);                                   \
        (SG) = __builtin_fmaf(nwc, m4, __builtin_fmaf(nwc, tm, (SG)));       \
        float tg = __builtin_fmaf(2.0f, g2, g1);                             \
        tg = __builtin_fmaf(2.0f, g3, tg);                                   \
        (IV) = __builtin_fmaf(w, g4, __builtin_fmaf(w, tg, (IV)));           \
    } while (0)

__global__ __launch_bounds__(64, 1) void sird_kernel(const float* __restrict__ alpha,
                                                     float* __restrict__ out) {
    const int lane = threadIdx.x;             // 64 threads = 1 wave per block
    const int s = blockIdx.x * 64 + lane;     // scenario

    const float beta  = alpha[s * 3 + 0];
    const float gamma = alpha[s * 3 + 1];
    const float mu    = alpha[s * 3 + 2];

    const float c    = beta * (1.0f / N_POP);
    const float gm   = gamma + mu;
    const float ngm  = -gm;
    const float h2   = 0.5f;                  // h/2, h = 1
    const float nch2 = -0.5f * c;             // -c*h/2
    const float nch  = -c;                    // -c*h
    const float w    = 1.0f / 6.0f;
    const float nwc  = -c * (1.0f / 6.0f);
    const float kD   = mu / gm;               // gamma,mu > 0 a.s.
    const float kDN  = kD * (float)N_POP;
    const float nkc  = -kD / c;
    const float nk   = -kD;

    float sg = c * (N_POP - 1.0f);            // sigma = c*S
    float I  = 1.0f;

    // Per-lane output row: out[s][t] = (I_t, D_t). Two tsteps per 16B store.
    float4* __restrict__ op4 = (float4*)((float2*)out + (size_t)s * T_PTS);

#pragma unroll 16
    for (int k = 0; k < T_PTS / 2; ++k) {
        const float i0 = I;
        const float d0 = __builtin_fmaf(nkc, sg, __builtin_fmaf(nk, I, kDN));
        RK4_STEP(sg, I);                       // even t -> odd t
        const float d1 = __builtin_fmaf(nkc, sg, __builtin_fmaf(nk, I, kDN));
        op4[k] = make_float4(i0, d0, I, d1);   // global_store_dwordx4, async
        RK4_STEP(sg, I);                       // odd t -> next even t
    }
}

extern "C" void kernel_launch(void* const* d_in, const int* in_sizes, int n_in,
                              void* d_out, int out_size, void* d_ws, size_t ws_size,
                              hipStream_t stream) {
    const float* alpha = (const float*)d_in[0];
    float* out = (float*)d_out;
    sird_kernel<<<dim3(T_PTS / 64), dim3(64), 0, stream>>>(alpha, out);
}

// Round 3
// 152.886 us; speedup vs baseline: 1.0991x; 1.0991x over previous
//
#include <hip/hip_runtime.h>

// SIRD RK4, round 16: shortened critical path ("g-free" RK4) in the R13
// producer/consumer structure (stride-2 handoff, SoA b32 LDS writes).
//
// Model fixed by R13/R14/R15: lone-wave time = max(issue: slots x 4 cyc,
// chain: crit-path x ~8.8 cyc). R13 crit=12 -> 115 cyc/tstep. R15 showed
// scattered-store issue (~28 cyc/tstep) must stay off the serial wave.
//
// g-elimination FROM THE CHAIN (not the op count): g_j = m_j - gm*i_j, so
//   i_{j+1} = fma(h_j, m_j, pre_j),  pre_j = fma(-gm*h_j, i_j, I)  [parallel]
//   I' = I + (1/6)Sm - (gm/6)Si,  Sm = m1+2m2+2m3+m4, Si = I+2i2+2i3+i4
// New dependent cycle: m1->i2->m2->i3->m3->i4->m4->Sm->{sg',I'} = 9 ops
// (was 12), still 22 ops total -> 13 off-chain fillers for in-order issue.
// NOT bit-identical to R13 (reassociated); truncation error of h=1 dominates.
//
// State (sigma, I), sigma = c*S. D from RK4-preserved invariant:
// D = fma(-kD/c, sigma, fma(-kD, I, kD*N)).

#define N_POP 1.0e7f
#define T_PTS 2048
#define KSEG 32                  // LDS slots per segment
#define SEG_T (KSEG * 2)         // tsteps covered per segment (stride 2)
#define NSEG (T_PTS / SEG_T)     // 32 segments

// One RK4 step (h=1), 22 ops, 9-op dependent cycle. Updates SG, IV in place.
#define RK4F(SG, IV)                                                         \
    do {                                                                     \
        const float pre1 = __builtin_fmaf(nh2gm, (IV), (IV));                \
        const float m1   = (SG) * (IV);                          /* c1 */    \
        const float s2   = __builtin_fmaf(nch2, m1, (SG));                   \
        const float i2   = __builtin_fmaf(h2, m1, pre1);         /* c2 */    \
        const float pre2 = __builtin_fmaf(nh2gm, i2, (IV));                  \
        const float sip1 = __builtin_fmaf(2.0f, i2, (IV));                   \
        const float m2   = s2 * i2;                              /* c3 */    \
        const float s3   = __builtin_fmaf(nch2, m2, (SG));                   \
        const float smp1 = __builtin_fmaf(2.0f, m2, m1);                     \
        const float i3   = __builtin_fmaf(h2, m2, pre2);         /* c4 */    \
        const float pre3 = __builtin_fmaf(ngm, i3, (IV));                    \
        const float sip2 = __builtin_fmaf(2.0f, i3, sip1);                   \
        const float m3   = s3 * i3;                              /* c5 */    \
        const float s4   = __builtin_fmaf(nch, m3, (SG));                    \
        const float smp2 = __builtin_fmaf(2.0f, m3, smp1);                   \
        const float i4   = m3 + pre3;                            /* c6 */    \
        const float si   = sip2 + i4;                                        \
        const float a    = __builtin_fmaf(nwgm, si, (IV));                   \
        const float m4   = s4 * i4;                              /* c7 */    \
        const float sm   = smp2 + m4;                            /* c8 */    \
        (SG) = __builtin_fmaf(nwc, sm, (SG));                    /* c9a */   \
        (IV) = __builtin_fmaf(w, sm, a);                         /* c9b */   \
    } while (0)

__global__ __launch_bounds__(128, 1) void sird_kernel(const float* __restrict__ alpha,
                                                      float* __restrict__ out) {
    const int lane = threadIdx.x & 63;
    const int wave = threadIdx.x >> 6;        // 0 = producer, 1 = consumer
    const int s = blockIdx.x * 64 + lane;     // scenario (same for both waves)

    // SoA, double-buffered: [buf][var][slot][lane], var 0=sigma 1=I. 32 KiB.
    __shared__ float buf[2][2][KSEG][64];

    const float beta  = alpha[s * 3 + 0];
    const float gamma = alpha[s * 3 + 1];
    const float mu    = alpha[s * 3 + 2];

    const float c     = beta * (1.0f / N_POP);
    const float gm    = gamma + mu;
    const float ngm   = -gm;
    const float h2    = 0.5f;                 // h/2, h = 1
    const float nch2  = -0.5f * c;            // -c*h/2
    const float nch   = -c;                   // -c*h
    const float nh2gm = -0.5f * gm;           // -gm*h/2
    const float w     = 1.0f / 6.0f;
    const float nwc   = -c * (1.0f / 6.0f);
    const float nwgm  = -gm * (1.0f / 6.0f);
    const float kD    = mu / gm;              // gamma,mu > 0 a.s.
    const float kDN   = kD * (float)N_POP;
    const float nkc   = -kD / c;
    const float nk    = -kD;

    float sg = c * (N_POP - 1.0f);            // sigma = c*S
    float I  = 1.0f;

    float2* __restrict__ orow = (float2*)out + (size_t)s * T_PTS;

    for (int seg = 0; seg <= NSEG; ++seg) {
        if (wave == 0) {
            if (seg < NSEG) {
                float* bsg = &buf[seg & 1][0][0][lane];
                float* bI  = &buf[seg & 1][1][0][lane];
#pragma unroll
                for (int k = 0; k < KSEG; ++k) {
                    bsg[k * 64] = sg;          // ds_write_b32, immediate offset
                    bI [k * 64] = I;
                    RK4F(sg, I);               // even -> odd
                    RK4F(sg, I);               // odd  -> next even
                }
            }
        } else {
            if (seg >= 1) {
                const float* qsg = &buf[(seg - 1) & 1][0][0][lane];
                const float* qI  = &buf[(seg - 1) & 1][1][0][lane];
                float2* op = orow + (size_t)(seg - 1) * SEG_T;
#pragma unroll
                for (int k = 0; k < KSEG; ++k) {
                    float sgv = qsg[k * 64];
                    float Iv  = qI [k * 64];
                    const float D0 = __builtin_fmaf(nkc, sgv,
                                     __builtin_fmaf(nk, Iv, kDN));
                    op[2 * k] = make_float2(Iv, D0);
                    RK4F(sgv, Iv);             // identical recompute of odd t
                    const float D1 = __builtin_fmaf(nkc, sgv,
                                     __builtin_fmaf(nk, Iv, kDN));
                    op[2 * k + 1] = make_float2(Iv, D1);
                }
            }
        }
        __syncthreads();
    }
}

extern "C" void kernel_launch(void* const* d_in, const int* in_sizes, int n_in,
                              void* d_out, int out_size, void* d_ws, size_t ws_size,
                              hipStream_t stream) {
    const float* alpha = (const float*)d_in[0];
    float* out = (float*)d_out;
    sird_kernel<<<dim3(T_PTS / 64), dim3(128), 0, stream>>>(alpha, out);
}